// Round 17
// baseline (231.722 us; speedup 1.0000x reference)
//
#include <hip/hip_runtime.h>

typedef unsigned short u16;
typedef unsigned int   u32;
typedef __attribute__((ext_vector_type(8))) __bf16 bf16x8;
typedef __attribute__((ext_vector_type(4))) float  f32x4;

#define DEV __device__ __forceinline__

namespace {

constexpr int B_  = 32;
constexpr int L_  = 512;
constexpr int P_  = 96;
constexpr int C_  = 512;
constexpr int K_  = 8;
constexpr int NL_ = 2;
constexpr int DF_ = 512;
constexpr int CK_ = 64;
constexpr float EPS_ = 1e-5f;

DEV float bf2f(u16 u){ union { u32 i; float f; } t; t.i = ((u32)u) << 16; return t.f; }
DEV u16 f2bf(float f){ union { float f; u32 i; } t; t.f = f;
  u32 r = t.i + 0x7fffu + ((t.i >> 16) & 1u); return (u16)(r >> 16); }
DEV u16 f2bfn(float f){ __bf16 h = (__bf16)f; u16 u; __builtin_memcpy(&u, &h, 2); return u; }
// dual-dtype load: bf==1 -> source is bf16 (u16), else fp32
DEV float LD(const void* p, size_t i, int bf){
  return bf ? bf2f(((const u16*)p)[i]) : ((const float*)p)[i];
}

// ---------------- dtype probe: bf16 low-half exponent signature ----------------
__global__ __launch_bounds__(256) void k_probe(const u32* __restrict__ x, int* __restrict__ flag){
  int cnt = 0;
  for (int i = threadIdx.x; i < 4096; i += 256){
    u32 w = x[i];
    u32 e = (w >> 7) & 0xFFu;
    cnt += (e >= 0x70u && e <= 0x8Fu) ? 1 : 0;
  }
#pragma unroll
  for (int o = 32; o > 0; o >>= 1) cnt += __shfl_xor(cnt, o);
  __shared__ int s[4];
  if ((threadIdx.x & 63) == 0) s[threadIdx.x >> 6] = cnt;
  __syncthreads();
  if (threadIdx.x == 0) flag[0] = (s[0] + s[1] + s[2] + s[3] > 2048) ? 1 : 0;
}

// ---------------- cluster argsort (stable counting sort) ----------------
__global__ __launch_bounds__(512) void k_sort(const int* __restrict__ cid, int* __restrict__ idx){
  __shared__ int bkt[C_];
  __shared__ int cnt[K_];
  __shared__ int off[K_];
  int c = threadIdx.x;
  int v = cid[c] % K_; if (v < 0) v += K_;
  bkt[c] = v;
  __syncthreads();
  if (c < K_){ int n = 0; for (int i = 0; i < C_; i++) n += (bkt[i] == c); cnt[c] = n; }
  __syncthreads();
  if (c == 0){ int s = 0; for (int k = 0; k < K_; k++){ off[k] = s; s += cnt[k]; } }
  __syncthreads();
  int r = 0;
  for (int i = 0; i < c; i++) r += (bkt[i] == bkt[c]);
  idx[off[bkt[c]] + r] = c;
}

// ---------------- batched transpose + cast to bf16: in[z][R][C] -> out[z][C][R] ----------------
__global__ __launch_bounds__(256) void k_trans(const void* __restrict__ in, u16* __restrict__ out,
                                               int R, int Cn, const int* __restrict__ flagp){
  __shared__ u16 t[32][36];
  int bf = *flagp;
  int z = blockIdx.z;
  int r0 = blockIdx.y * 32, c0 = blockIdx.x * 32;
  size_t base = (size_t)z * R * Cn;
  int tid = threadIdx.x;
  int i = tid >> 3, j4 = (tid & 7) * 4;
  size_t off = base + (size_t)(r0 + i) * Cn + c0 + j4;
  if (bf){
    ushort4 v = *reinterpret_cast<const ushort4*>((const u16*)in + off);
    t[i][j4 + 0] = v.x; t[i][j4 + 1] = v.y; t[i][j4 + 2] = v.z; t[i][j4 + 3] = v.w;
  } else {
    float4 v = *reinterpret_cast<const float4*>((const float*)in + off);
    t[i][j4 + 0] = f2bf(v.x); t[i][j4 + 1] = f2bf(v.y); t[i][j4 + 2] = f2bf(v.z); t[i][j4 + 3] = f2bf(v.w);
  }
  __syncthreads();
  ushort4 w;
  w.x = t[j4 + 0][i]; w.y = t[j4 + 1][i]; w.z = t[j4 + 2][i]; w.w = t[j4 + 3][i];
  *reinterpret_cast<ushort4*>(out + base + (size_t)(c0 + i) * R + r0 + j4) = w;
}

// ---------------- RevIN stats stage 1: partial sums over 32-timestep slices ----------------
__global__ __launch_bounds__(512) void k_stats1(const void* __restrict__ x,
                                                float* __restrict__ psum, float* __restrict__ psq,
                                                const int* __restrict__ flagp){
  int bf = *flagp;
  int ls = blockIdx.x, b = blockIdx.y, c = threadIdx.x;
  size_t base = ((size_t)b * L_ + (size_t)ls * 32) * C_ + c;
  float s = 0.f, sq = 0.f;
#pragma unroll 8
  for (int l = 0; l < 32; l++){
    float v = LD(x, base + (size_t)l * C_, bf);
    s += v; sq += v * v;
  }
  int o = (b * 16 + ls) * C_ + c;
  psum[o] = s; psq[o] = sq;
}

// ---------------- RevIN stats stage 2: fold partials -> mean/std + fused scale/bias ----------------
__global__ __launch_bounds__(512) void k_stats2(const float* __restrict__ psum, const float* __restrict__ psq,
                                                const void* __restrict__ revw, const void* __restrict__ revb,
                                                float* __restrict__ meanw, float* __restrict__ stdw,
                                                float* __restrict__ scalew, float* __restrict__ biasw,
                                                const int* __restrict__ flagp){
  int bf = *flagp;
  int b = blockIdx.x, c = threadIdx.x;
  float s = 0.f, sq = 0.f;
#pragma unroll
  for (int i = 0; i < 16; i++){
    s  += psum[(b * 16 + i) * C_ + c];
    sq += psq [(b * 16 + i) * C_ + c];
  }
  float m = s * (1.f / L_);
  float var = sq * (1.f / L_) - m * m;
  float sd = sqrtf(var + EPS_);
  meanw[b * C_ + c] = m;
  stdw [b * C_ + c] = sd;
  float sc = LD(revw, c, bf) / sd;
  scalew[b * C_ + c] = sc;
  biasw [b * C_ + c] = LD(revb, c, bf) - m * sc;
}

// ---------------- gather + RevIN normalize (LDS-staged, coalesced) -> xg f32 [K][B][L][CK] ----------------
__global__ __launch_bounds__(256) void k_gather(const void* __restrict__ x, const int* __restrict__ idx,
                                                const float* __restrict__ scalew, const float* __restrict__ biasw,
                                                float* __restrict__ xg, const int* __restrict__ flagp){
  __shared__ float row[576];          // 512 + c>>3 skew padding
  int bf = *flagp;
  int lt = blockIdx.x, b = blockIdx.y;
  int tid = threadIdx.x;
  int oc0 = tid, oc1 = tid + 256;
  int c0 = idx[oc0], c1 = idx[oc1];
  float sc0 = scalew[b * C_ + c0], bs0 = biasw[b * C_ + c0];
  float sc1 = scalew[b * C_ + c1], bs1 = biasw[b * C_ + c1];
  int p0 = c0 + (c0 >> 3), p1 = c1 + (c1 >> 3);
  int k0 = oc0 >> 6, j0 = oc0 & 63;
  int k1 = oc1 >> 6, j1 = oc1 & 63;

  for (int r = 0; r < 16; r++){
    int l = lt * 16 + r;
    size_t base = ((size_t)b * L_ + l) * C_;
    if (bf){
      int i4 = tid * 2;
      ushort2 v = *reinterpret_cast<const ushort2*>((const u16*)x + base + i4);
      int a0 = i4, a1 = i4 + 1;
      row[a0 + (a0 >> 3)] = bf2f(v.x);
      row[a1 + (a1 >> 3)] = bf2f(v.y);
    } else {
      int i2 = tid * 2;
      float2 v = *reinterpret_cast<const float2*>((const float*)x + base + i2);
      int a0 = i2, a1 = i2 + 1;
      row[a0 + (a0 >> 3)] = v.x;
      row[a1 + (a1 >> 3)] = v.y;
    }
    __syncthreads();
    float o0 = row[p0] * sc0 + bs0;
    float o1 = row[p1] * sc1 + bs1;
    xg[(((size_t)k0 * B_ + b) * L_ + l) * CK_ + j0] = o0;
    xg[(((size_t)k1 * B_ + b) * L_ + l) * CK_ + j1] = o1;
    __syncthreads();
  }
}

// ---------------- LN over channels + transpose-cast: xg f32 [kb][L][64] -> dst bf16 [kb][64][L] ----------------
__global__ __launch_bounds__(256) void k_lnt(const float* __restrict__ src, u16* __restrict__ dst,
                                             const void* __restrict__ g, const void* __restrict__ bb,
                                             int layer, int use_ln, const int* __restrict__ flagp){
  __shared__ float tile[64][65];
  int bf = *flagp;
  int z = blockIdx.x;
  int kb = z >> 3, lt = z & 7;
  int k = kb >> 5;
  const float* s = src + (size_t)kb * L_ * CK_ + (size_t)lt * 64 * CK_;
  int tid = threadIdx.x, lane = tid & 63, w = tid >> 6;
  float gj = 1.f, bj = 0.f;
  if (use_ln){
    gj = LD(g,  (size_t)(k * NL_ + layer) * CK_ + lane, bf);
    bj = LD(bb, (size_t)(k * NL_ + layer) * CK_ + lane, bf);
  }
  for (int i = 0; i < 16; i++){
    int row = w * 16 + i;
    float v = s[(size_t)row * CK_ + lane];
    float sum = v, sq = v * v;
#pragma unroll
    for (int o = 32; o > 0; o >>= 1){ sum += __shfl_xor(sum, o); sq += __shfl_xor(sq, o); }
    float nv = v;
    if (use_ln){
      float m = sum * (1.f / 64.f);
      float var = sq * (1.f / 64.f) - m * m;
      nv = (v - m) * rsqrtf(var + EPS_) * gj + bj;
    }
    tile[row][lane] = nv;
  }
  __syncthreads();
  int c = tid >> 2, seg = tid & 3;
  union { u16 s[8]; uint4 q; } u0, u1;
#pragma unroll
  for (int e = 0; e < 8; e++) u0.s[e] = f2bf(tile[seg * 16 + e][c]);
#pragma unroll
  for (int e = 0; e < 8; e++) u1.s[e] = f2bf(tile[seg * 16 + 8 + e][c]);
  u16* d = dst + (size_t)kb * CK_ * L_ + (size_t)c * L_ + lt * 64 + seg * 16;
  *reinterpret_cast<uint4*>(d)     = u0.q;
  *reinterpret_cast<uint4*>(d + 8) = u1.q;
}

// ---------------- fused mixer layer: time-mix + LN2 (LDS handoff) + FFN + LN1next/transpose ----------------
// residual carried in registers across phases (no phase-2 xg store, no phase-4 xg re-read)
__global__ __launch_bounds__(256, 4) void k_mix(const u16* __restrict__ WtT, const u16* __restrict__ xin,
                                                float* __restrict__ xg,
                                                const void* __restrict__ bt,
                                                const void* __restrict__ ln2g, const void* __restrict__ ln2b,
                                                const u16* __restrict__ w1t, const u16* __restrict__ w2t,
                                                const void* __restrict__ bf1, const void* __restrict__ bf2,
                                                const void* __restrict__ ln1g, const void* __restrict__ ln1b,
                                                u16* __restrict__ xout, int layer,
                                                const int* __restrict__ flagp){
  __shared__ __align__(16) char lds[36864];
  u16* a_lds = (u16*)lds;              // [0,10240)   128*40
  u16* b_lds = (u16*)(lds + 10240);    // [10240,15360) 64*40
  u16* sm    = (u16*)lds;              // [0,18432)   128*72 (after time-mix)
  u16* wl    = (u16*)(lds + 18432);    // [18432,36864) 2 x 64*72
  int bf = *flagp;
  // XCD pinning
  int bid = blockIdx.x;
  int k = bid & 7, rr = bid >> 3;
  int b = rr & 31, mb = rr >> 5;       // mb in 0..3
  int m0 = mb * 128;
  const int klb = k * NL_ + layer;
  int kb = k * B_ + b;
  const u16* A  = WtT + ((size_t)klb * L_ + m0) * L_;
  const u16* Bm = xin + (size_t)kb * CK_ * L_;
  const u16* w1p = w1t + (size_t)klb * DF_ * CK_;
  const u16* w2p = w2t + (size_t)klb * CK_ * DF_;
  int tid = threadIdx.x, lane = tid & 63, w = tid >> 6, grp = lane >> 4, ln = lane & 15;

  // ===== phase 1: time mix =====
  int sa0 = tid, sa1 = tid + 256;
  int ra0 = sa0 >> 2, qa0 = (sa0 & 3) * 8;
  int ra1 = sa1 >> 2, qa1 = (sa1 & 3) * 8;
  int rb0 = tid >> 2, qb0 = (tid & 3) * 8;

  f32x4 acc[2][4];
#pragma unroll
  for (int i = 0; i < 2; i++)
#pragma unroll
    for (int j = 0; j < 4; j++) acc[i][j] = (f32x4){0.f, 0.f, 0.f, 0.f};

  uint4 va0 = *reinterpret_cast<const uint4*>(A + (size_t)ra0 * L_ + qa0);
  uint4 va1 = *reinterpret_cast<const uint4*>(A + (size_t)ra1 * L_ + qa1);
  uint4 vb0 = *reinterpret_cast<const uint4*>(Bm + (size_t)rb0 * L_ + qb0);

  for (int kk = 0; kk < 16; kk++){
    *reinterpret_cast<uint4*>(&a_lds[ra0 * 40 + qa0]) = va0;
    *reinterpret_cast<uint4*>(&a_lds[ra1 * 40 + qa1]) = va1;
    *reinterpret_cast<uint4*>(&b_lds[rb0 * 40 + qb0]) = vb0;
    uint4 na0, na1, nb0;
    if (kk < 15){
      int c0 = (kk + 1) * 32;
      na0 = *reinterpret_cast<const uint4*>(A + (size_t)ra0 * L_ + c0 + qa0);
      na1 = *reinterpret_cast<const uint4*>(A + (size_t)ra1 * L_ + c0 + qa1);
      nb0 = *reinterpret_cast<const uint4*>(Bm + (size_t)rb0 * L_ + c0 + qb0);
    }
    __syncthreads();
    bf16x8 af[2], bfr[4];
#pragma unroll
    for (int mt = 0; mt < 2; mt++)
      af[mt] = *reinterpret_cast<bf16x8*>(&a_lds[(w * 32 + mt * 16 + ln) * 40 + grp * 8]);
#pragma unroll
    for (int ct = 0; ct < 4; ct++)
      bfr[ct] = *reinterpret_cast<bf16x8*>(&b_lds[(ct * 16 + ln) * 40 + grp * 8]);
#pragma unroll
    for (int mt = 0; mt < 2; mt++)
#pragma unroll
      for (int ct = 0; ct < 4; ct++)
        acc[mt][ct] = __builtin_amdgcn_mfma_f32_16x16x32_bf16(af[mt], bfr[ct], acc[mt][ct], 0, 0, 0);
    __syncthreads();
    va0 = na0; va1 = na1; vb0 = nb0;
  }

  // weight staging indices (512 uint4 per matrix over 256 threads = 2 each)
  int wr0 = tid >> 3, wq0 = (tid & 7) * 8;
  int wr1 = wr0 + 32;
  // prefetch ft=0 weights (hide under LN2/epilogue)
  uint4 g1a = *reinterpret_cast<const uint4*>(w1p + (size_t)wr0 * CK_ + wq0);
  uint4 g1b = *reinterpret_cast<const uint4*>(w1p + (size_t)wr1 * CK_ + wq0);
  uint4 g2a = *reinterpret_cast<const uint4*>(w2p + (size_t)wr0 * DF_ + wq0);
  uint4 g2b = *reinterpret_cast<const uint4*>(w2p + (size_t)wr1 * DF_ + wq0);

  // ===== phase 2: residual (read-only xg) + LN2 -> sm; keep residual in regs =====
  float res[2][4][4];   // [mt][ct][r]
  {
    float g2[4], b2[4];
#pragma unroll
    for (int ct = 0; ct < 4; ct++){
      int cc = ct * 16 + ln;
      g2[ct] = LD(ln2g, (size_t)klb * CK_ + cc, bf);
      b2[ct] = LD(ln2b, (size_t)klb * CK_ + cc, bf);
    }
    const float* xgp = xg + (size_t)kb * L_ * CK_;
#pragma unroll
    for (int mt = 0; mt < 2; mt++){
#pragma unroll
      for (int r = 0; r < 4; r++){
        int rl = w * 32 + mt * 16 + grp * 4 + r;
        int m = m0 + rl;
        float bias = LD(bt, (size_t)klb * L_ + m, bf);
        float s = 0.f, sq = 0.f;
#pragma unroll
        for (int ct = 0; ct < 4; ct++){
          int cc = ct * 16 + ln;
          float y = fmaxf(acc[mt][ct][r] + bias, 0.f);
          float v = xgp[(size_t)m * CK_ + cc] + y;
          res[mt][ct][r] = v;
          s += v; sq += v * v;
        }
#pragma unroll
        for (int o = 1; o < 16; o <<= 1){ s += __shfl_xor(s, o); sq += __shfl_xor(sq, o); }
        float mean = s * (1.f / 64.f);
        float var = sq * (1.f / 64.f) - mean * mean;
        float rstd = rsqrtf(var + EPS_);
#pragma unroll
        for (int ct = 0; ct < 4; ct++){
          int cc = ct * 16 + ln;
          sm[rl * 72 + cc] = f2bfn((res[mt][ct][r] - mean) * rstd * g2[ct] + b2[ct]);
        }
      }
    }
  }
  __syncthreads();

  // ===== phase 3: FFN (4 waves x 32 rows) =====
  bf16x8 faf[2][2];
#pragma unroll
  for (int mt = 0; mt < 2; mt++)
#pragma unroll
    for (int ks = 0; ks < 2; ks++)
      faf[mt][ks] = *reinterpret_cast<bf16x8*>(&sm[(w * 32 + mt * 16 + ln) * 72 + ks * 32 + grp * 8]);
  __syncthreads();   // sm rows now reusable as h (wave-private)

  f32x4 acc2[2][4];
#pragma unroll
  for (int i = 0; i < 2; i++)
#pragma unroll
    for (int j = 0; j < 4; j++) acc2[i][j] = (f32x4){0.f, 0.f, 0.f, 0.f};

#pragma unroll
  for (int ft = 0; ft < 8; ft++){
    *reinterpret_cast<uint4*>(&wl[wr0 * 72 + wq0]) = g1a;
    *reinterpret_cast<uint4*>(&wl[wr1 * 72 + wq0]) = g1b;
    *reinterpret_cast<uint4*>(&wl[4608 + wr0 * 72 + wq0]) = g2a;
    *reinterpret_cast<uint4*>(&wl[4608 + wr1 * 72 + wq0]) = g2b;
    if (ft < 7){
      g1a = *reinterpret_cast<const uint4*>(w1p + (size_t)((ft + 1) * 64 + wr0) * CK_ + wq0);
      g1b = *reinterpret_cast<const uint4*>(w1p + (size_t)((ft + 1) * 64 + wr1) * CK_ + wq0);
      g2a = *reinterpret_cast<const uint4*>(w2p + (size_t)wr0 * DF_ + (ft + 1) * 64 + wq0);
      g2b = *reinterpret_cast<const uint4*>(w2p + (size_t)wr1 * DF_ + (ft + 1) * 64 + wq0);
    }
    __syncthreads();

    f32x4 acc1[2][4];
#pragma unroll
    for (int i = 0; i < 2; i++)
#pragma unroll
      for (int j = 0; j < 4; j++) acc1[i][j] = (f32x4){0.f, 0.f, 0.f, 0.f};
#pragma unroll
    for (int ks = 0; ks < 2; ks++)
#pragma unroll
      for (int n = 0; n < 4; n++){
        bf16x8 bb = *reinterpret_cast<bf16x8*>(&wl[(n * 16 + ln) * 72 + ks * 32 + grp * 8]);
#pragma unroll
        for (int mt = 0; mt < 2; mt++)
          acc1[mt][n] = __builtin_amdgcn_mfma_f32_16x16x32_bf16(faf[mt][ks], bb, acc1[mt][n], 0, 0, 0);
      }
#pragma unroll
    for (int n = 0; n < 4; n++){
      float bias = LD(bf1, (size_t)klb * DF_ + ft * 64 + n * 16 + ln, bf);
#pragma unroll
      for (int mt = 0; mt < 2; mt++)
#pragma unroll
        for (int r = 0; r < 4; r++){
          float v = fmaxf(acc1[mt][n][r] + bias, 0.f);
          sm[(w * 32 + mt * 16 + grp * 4 + r) * 72 + n * 16 + ln] = f2bfn(v);
        }
    }
#pragma unroll
    for (int ks = 0; ks < 2; ks++){
      bf16x8 hh[2];
#pragma unroll
      for (int mt = 0; mt < 2; mt++)
        hh[mt] = *reinterpret_cast<bf16x8*>(&sm[(w * 32 + mt * 16 + ln) * 72 + ks * 32 + grp * 8]);
#pragma unroll
      for (int n = 0; n < 4; n++){
        bf16x8 bb = *reinterpret_cast<bf16x8*>(&wl[4608 + (n * 16 + ln) * 72 + ks * 32 + grp * 8]);
#pragma unroll
        for (int mt = 0; mt < 2; mt++)
          acc2[mt][n] = __builtin_amdgcn_mfma_f32_16x16x32_bf16(hh[mt], bb, acc2[mt][n], 0, 0, 0);
      }
    }
    __syncthreads();
  }

  // ===== phase 4: residual (from regs) + next-layer LN1 (or cast) + transposed out =====
  const int next = layer + 1;
  const int use_ln = (next < NL_);
  float g1v[4], b1v[4], b2v[4];
#pragma unroll
  for (int n = 0; n < 4; n++){
    int cc = n * 16 + ln;
    b2v[n] = LD(bf2, (size_t)klb * CK_ + cc, bf);
    if (use_ln){
      g1v[n] = LD(ln1g, (size_t)(k * NL_ + next) * CK_ + cc, bf);
      b1v[n] = LD(ln1b, (size_t)(k * NL_ + next) * CK_ + cc, bf);
    } else { g1v[n] = 1.f; b1v[n] = 0.f; }
  }
  float* xgp = xg + ((size_t)kb * L_ + m0) * CK_;
#pragma unroll
  for (int mt = 0; mt < 2; mt++){
#pragma unroll
    for (int r = 0; r < 4; r++){
      int rl = w * 32 + mt * 16 + grp * 4 + r;
      float v[4];
      float s = 0.f, sq = 0.f;
#pragma unroll
      for (int n = 0; n < 4; n++){
        int cc = n * 16 + ln;
        float t = res[mt][n][r] + acc2[mt][n][r] + b2v[n];
        if (use_ln) xgp[(size_t)rl * CK_ + cc] = t;   // only needed for next layer
        v[n] = t; s += t; sq += t * t;
      }
      float mean = 0.f, rstd = 1.f;
      if (use_ln){
#pragma unroll
        for (int o = 1; o < 16; o <<= 1){ s += __shfl_xor(s, o); sq += __shfl_xor(sq, o); }
        mean = s * (1.f / 64.f);
        float var = sq * (1.f / 64.f) - mean * mean;
        rstd = rsqrtf(var + EPS_);
      }
#pragma unroll
      for (int n = 0; n < 4; n++){
        int cc = n * 16 + ln;
        sm[cc * 136 + rl] = f2bfn((v[n] - mean) * rstd * g1v[n] + b1v[n]);
      }
    }
  }
  __syncthreads();
  // coalesced transpose-out: xout[kb][c][m0 + off]
  u16* xsw = xout + (size_t)kb * CK_ * L_ + m0;
#pragma unroll
  for (int i = 0; i < 4; i++){
    int s = tid + i * 256;
    int c = s >> 4, off = (s & 15) * 8;
    *reinterpret_cast<uint4*>(xsw + (size_t)c * L_ + off) =
      *reinterpret_cast<uint4*>(&sm[c * 136 + off]);
  }
}

// ---------------- output projection + scatter + RevIN denorm ----------------
__global__ __launch_bounds__(384) void k_out(const u16* __restrict__ WoT, const u16* __restrict__ xgt,
                                             const int* __restrict__ idx, const void* __restrict__ bout,
                                             const void* __restrict__ revw, const void* __restrict__ revb,
                                             const float* __restrict__ meanw, const float* __restrict__ stdw,
                                             void* __restrict__ out, const int* __restrict__ flagp){
  __shared__ u16 a_lds[96 * 40];
  __shared__ u16 b_lds[64 * 40];
  int bf = *flagp;
  int b = blockIdx.x, k = blockIdx.y;
  int kb = k * B_ + b;
  const u16* A  = WoT + (size_t)k * P_ * L_;
  const u16* Bm = xgt + (size_t)kb * CK_ * L_;
  int tid = threadIdx.x, lane = tid & 63, w = tid >> 6, grp = lane >> 4, ln = lane & 15;
  f32x4 acc[4];
#pragma unroll
  for (int j = 0; j < 4; j++) acc[j] = (f32x4){0.f, 0.f, 0.f, 0.f};

  for (int kk = 0; kk < 16; kk++){
    {
      int row = tid >> 2, q = tid & 3;
      *reinterpret_cast<uint4*>(&a_lds[row * 40 + q * 8]) =
        *reinterpret_cast<const uint4*>(A + (size_t)row * L_ + kk * 32 + q * 8);
    }
    if (tid < 256){
      int row = tid >> 2, q = tid & 3;
      *reinterpret_cast<uint4*>(&b_lds[row * 40 + q * 8]) =
        *reinterpret_cast<const uint4*>(Bm + (size_t)row * L_ + kk * 32 + q * 8);
    }
    __syncthreads();
    bf16x8 af = *reinterpret_cast<bf16x8*>(&a_lds[(w * 16 + ln) * 40 + grp * 8]);
#pragma unroll
    for (int n = 0; n < 4; n++){
      bf16x8 bfr = *reinterpret_cast<bf16x8*>(&b_lds[(n * 16 + ln) * 40 + grp * 8]);
      acc[n] = __builtin_amdgcn_mfma_f32_16x16x32_bf16(af, bfr, acc[n], 0, 0, 0);
    }
    __syncthreads();
  }
#pragma unroll
  for (int n = 0; n < 4; n++){
    int j = n * 16 + ln;
    int c = idx[k * CK_ + j];
    float rw = LD(revw, c, bf), rb = LD(revb, c, bf);
    float sd = stdw[b * C_ + c], mn = meanw[b * C_ + c];
#pragma unroll
    for (int r = 0; r < 4; r++){
      int p = w * 16 + grp * 4 + r;
      float y = acc[n][r] + LD(bout, (size_t)k * P_ + p, bf);
      float val = (y - rb) / rw * sd + mn;
      size_t oi = ((size_t)b * P_ + p) * C_ + c;
      if (bf) ((u16*)out)[oi] = f2bf(val);
      else    ((float*)out)[oi] = val;
    }
  }
}

} // namespace

extern "C" void kernel_launch(void* const* d_in, const int* in_sizes, int n_in,
                              void* d_out, int out_size, void* d_ws, size_t ws_size,
                              hipStream_t stream){
  const void* x    = d_in[0];
  const int*  cid  = (const int*)d_in[1];
  const void* revw = d_in[2];
  const void* revb = d_in[3];
  const void* Wt   = d_in[4];
  const void* bt   = d_in[5];
  const void* ln1g = d_in[6];
  const void* ln1b = d_in[7];
  const void* Wf1  = d_in[8];
  const void* bf1  = d_in[9];
  const void* Wf2  = d_in[10];
  const void* bf2  = d_in[11];
  const void* ln2g = d_in[12];
  const void* ln2b = d_in[13];
  const void* Wout = d_in[14];
  const void* bout = d_in[15];
  char* ws = (char*)d_ws;

  int*   flag   = (int*)  (ws + 0);
  int*   idxp   = (int*)  (ws + 64);
  float* meanw  = (float*)(ws + 4096);
  float* stdw   = (float*)(ws + 69632);
  float* scalew = (float*)(ws + 135168);
  float* biasw  = (float*)(ws + 200704);
  float* psum   = (float*)(ws + 266240);    // 1MB
  float* psq    = (float*)(ws + 1314816);   // 1MB
  float* xg     = (float*)(ws + 2363392);   // 33.5MB
  u16*   xsA    = (u16*)  (ws + 35917824);  // ping-pong activation A ([kb][c][l], 16.8MB)
  u16*   WtT    = (u16*)  (ws + 52695040);
  u16*   Wf1T   = (u16*)  (ws + 61083648);
  u16*   Wf2T   = (u16*)  (ws + 62132224);
  u16*   WoT    = (u16*)  (ws + 63180800);
  u16*   xsB    = (u16*)  (ws + 63967232);  // ping-pong activation B; ends 80744448

  k_probe<<<1, 256, 0, stream>>>((const u32*)x, flag);
  k_sort<<<1, 512, 0, stream>>>(cid, idxp);
  k_trans<<<dim3(16, 16, 16), 256, 0, stream>>>(Wt,   WtT,  512, 512, flag);
  k_trans<<<dim3(16,  2, 16), 256, 0, stream>>>(Wf1,  Wf1T,  64, 512, flag);
  k_trans<<<dim3( 2, 16, 16), 256, 0, stream>>>(Wf2,  Wf2T, 512,  64, flag);
  k_trans<<<dim3( 3, 16,  8), 256, 0, stream>>>(Wout, WoT,  512,  96, flag);
  k_stats1<<<dim3(16, 32), 512, 0, stream>>>(x, psum, psq, flag);
  k_stats2<<<32, 512, 0, stream>>>(psum, psq, revw, revb, meanw, stdw, scalew, biasw, flag);
  k_gather<<<dim3(32, 32), 256, 0, stream>>>(x, idxp, scalew, biasw, xg, flag);

  // layer-0 LN1 + transpose -> xsA
  k_lnt<<<2048, 256, 0, stream>>>(xg, xsA, ln1g, ln1b, 0, 1, flag);
  // fused layers with ping-pong: L0 xsA->xsB, L1 xsB->xsA
  k_mix<<<1024, 256, 0, stream>>>(WtT, xsA, xg, bt, ln2g, ln2b, Wf1T, Wf2T,
                                  bf1, bf2, ln1g, ln1b, xsB, 0, flag);
  k_mix<<<1024, 256, 0, stream>>>(WtT, xsB, xg, bt, ln2g, ln2b, Wf1T, Wf2T,
                                  bf1, bf2, ln1g, ln1b, xsA, 1, flag);

  k_out<<<dim3(32, 8), 384, 0, stream>>>(WoT, xsA, idxp, bout, revw, revb, meanw, stdw, d_out, flag);
}

// Round 18
// 223.919 us; speedup vs baseline: 1.0348x; 1.0348x over previous
//
#include <hip/hip_runtime.h>

typedef unsigned short u16;
typedef unsigned int   u32;
typedef __attribute__((ext_vector_type(8))) __bf16 bf16x8;
typedef __attribute__((ext_vector_type(4))) float  f32x4;

#define DEV __device__ __forceinline__

namespace {

constexpr int B_  = 32;
constexpr int L_  = 512;
constexpr int P_  = 96;
constexpr int C_  = 512;
constexpr int K_  = 8;
constexpr int NL_ = 2;
constexpr int DF_ = 512;
constexpr int CK_ = 64;
constexpr float EPS_ = 1e-5f;

DEV float bf2f(u16 u){ union { u32 i; float f; } t; t.i = ((u32)u) << 16; return t.f; }
DEV u16 f2bf(float f){ union { float f; u32 i; } t; t.f = f;
  u32 r = t.i + 0x7fffu + ((t.i >> 16) & 1u); return (u16)(r >> 16); }
DEV u16 f2bfn(float f){ __bf16 h = (__bf16)f; u16 u; __builtin_memcpy(&u, &h, 2); return u; }
// dual-dtype load: bf==1 -> source is bf16 (u16), else fp32
DEV float LD(const void* p, size_t i, int bf){
  return bf ? bf2f(((const u16*)p)[i]) : ((const float*)p)[i];
}

// ---------------- dtype probe: bf16 low-half exponent signature ----------------
__global__ __launch_bounds__(256) void k_probe(const u32* __restrict__ x, int* __restrict__ flag){
  int cnt = 0;
  for (int i = threadIdx.x; i < 4096; i += 256){
    u32 w = x[i];
    u32 e = (w >> 7) & 0xFFu;
    cnt += (e >= 0x70u && e <= 0x8Fu) ? 1 : 0;
  }
#pragma unroll
  for (int o = 32; o > 0; o >>= 1) cnt += __shfl_xor(cnt, o);
  __shared__ int s[4];
  if ((threadIdx.x & 63) == 0) s[threadIdx.x >> 6] = cnt;
  __syncthreads();
  if (threadIdx.x == 0) flag[0] = (s[0] + s[1] + s[2] + s[3] > 2048) ? 1 : 0;
}

// ---------------- cluster argsort (stable counting sort) ----------------
__global__ __launch_bounds__(512) void k_sort(const int* __restrict__ cid, int* __restrict__ idx){
  __shared__ int bkt[C_];
  __shared__ int cnt[K_];
  __shared__ int off[K_];
  int c = threadIdx.x;
  int v = cid[c] % K_; if (v < 0) v += K_;
  bkt[c] = v;
  __syncthreads();
  if (c < K_){ int n = 0; for (int i = 0; i < C_; i++) n += (bkt[i] == c); cnt[c] = n; }
  __syncthreads();
  if (c == 0){ int s = 0; for (int k = 0; k < K_; k++){ off[k] = s; s += cnt[k]; } }
  __syncthreads();
  int r = 0;
  for (int i = 0; i < c; i++) r += (bkt[i] == bkt[c]);
  idx[off[bkt[c]] + r] = c;
}

// ---------------- batched transpose + cast to bf16: in[z][R][C] -> out[z][C][R] ----------------
__global__ __launch_bounds__(256) void k_trans(const void* __restrict__ in, u16* __restrict__ out,
                                               int R, int Cn, const int* __restrict__ flagp){
  __shared__ u16 t[32][36];
  int bf = *flagp;
  int z = blockIdx.z;
  int r0 = blockIdx.y * 32, c0 = blockIdx.x * 32;
  size_t base = (size_t)z * R * Cn;
  int tid = threadIdx.x;
  int i = tid >> 3, j4 = (tid & 7) * 4;
  size_t off = base + (size_t)(r0 + i) * Cn + c0 + j4;
  if (bf){
    ushort4 v = *reinterpret_cast<const ushort4*>((const u16*)in + off);
    t[i][j4 + 0] = v.x; t[i][j4 + 1] = v.y; t[i][j4 + 2] = v.z; t[i][j4 + 3] = v.w;
  } else {
    float4 v = *reinterpret_cast<const float4*>((const float*)in + off);
    t[i][j4 + 0] = f2bf(v.x); t[i][j4 + 1] = f2bf(v.y); t[i][j4 + 2] = f2bf(v.z); t[i][j4 + 3] = f2bf(v.w);
  }
  __syncthreads();
  ushort4 w;
  w.x = t[j4 + 0][i]; w.y = t[j4 + 1][i]; w.z = t[j4 + 2][i]; w.w = t[j4 + 3][i];
  *reinterpret_cast<ushort4*>(out + base + (size_t)(c0 + i) * R + r0 + j4) = w;
}

// ---------------- RevIN stats stage 1: partial sums over 32-timestep slices ----------------
__global__ __launch_bounds__(512) void k_stats1(const void* __restrict__ x,
                                                float* __restrict__ psum, float* __restrict__ psq,
                                                const int* __restrict__ flagp){
  int bf = *flagp;
  int ls = blockIdx.x, b = blockIdx.y, c = threadIdx.x;
  size_t base = ((size_t)b * L_ + (size_t)ls * 32) * C_ + c;
  float s = 0.f, sq = 0.f;
#pragma unroll 8
  for (int l = 0; l < 32; l++){
    float v = LD(x, base + (size_t)l * C_, bf);
    s += v; sq += v * v;
  }
  int o = (b * 16 + ls) * C_ + c;
  psum[o] = s; psq[o] = sq;
}

// ---------------- RevIN stats stage 2: fold partials -> mean/std + fused scale/bias ----------------
__global__ __launch_bounds__(512) void k_stats2(const float* __restrict__ psum, const float* __restrict__ psq,
                                                const void* __restrict__ revw, const void* __restrict__ revb,
                                                float* __restrict__ meanw, float* __restrict__ stdw,
                                                float* __restrict__ scalew, float* __restrict__ biasw,
                                                const int* __restrict__ flagp){
  int bf = *flagp;
  int b = blockIdx.x, c = threadIdx.x;
  float s = 0.f, sq = 0.f;
#pragma unroll
  for (int i = 0; i < 16; i++){
    s  += psum[(b * 16 + i) * C_ + c];
    sq += psq [(b * 16 + i) * C_ + c];
  }
  float m = s * (1.f / L_);
  float var = sq * (1.f / L_) - m * m;
  float sd = sqrtf(var + EPS_);
  meanw[b * C_ + c] = m;
  stdw [b * C_ + c] = sd;
  float sc = LD(revw, c, bf) / sd;
  scalew[b * C_ + c] = sc;
  biasw [b * C_ + c] = LD(revb, c, bf) - m * sc;
}

// ---------------- gather + RevIN normalize (LDS-staged, coalesced) -> xg f32 [K][B][L][CK] ----------------
__global__ __launch_bounds__(256) void k_gather(const void* __restrict__ x, const int* __restrict__ idx,
                                                const float* __restrict__ scalew, const float* __restrict__ biasw,
                                                float* __restrict__ xg, const int* __restrict__ flagp){
  __shared__ float row[576];          // 512 + c>>3 skew padding
  int bf = *flagp;
  int lt = blockIdx.x, b = blockIdx.y;
  int tid = threadIdx.x;
  int oc0 = tid, oc1 = tid + 256;
  int c0 = idx[oc0], c1 = idx[oc1];
  float sc0 = scalew[b * C_ + c0], bs0 = biasw[b * C_ + c0];
  float sc1 = scalew[b * C_ + c1], bs1 = biasw[b * C_ + c1];
  int p0 = c0 + (c0 >> 3), p1 = c1 + (c1 >> 3);
  int k0 = oc0 >> 6, j0 = oc0 & 63;
  int k1 = oc1 >> 6, j1 = oc1 & 63;

  for (int r = 0; r < 16; r++){
    int l = lt * 16 + r;
    size_t base = ((size_t)b * L_ + l) * C_;
    if (bf){
      int i4 = tid * 2;
      ushort2 v = *reinterpret_cast<const ushort2*>((const u16*)x + base + i4);
      int a0 = i4, a1 = i4 + 1;
      row[a0 + (a0 >> 3)] = bf2f(v.x);
      row[a1 + (a1 >> 3)] = bf2f(v.y);
    } else {
      int i2 = tid * 2;
      float2 v = *reinterpret_cast<const float2*>((const float*)x + base + i2);
      int a0 = i2, a1 = i2 + 1;
      row[a0 + (a0 >> 3)] = v.x;
      row[a1 + (a1 >> 3)] = v.y;
    }
    __syncthreads();
    float o0 = row[p0] * sc0 + bs0;
    float o1 = row[p1] * sc1 + bs1;
    xg[(((size_t)k0 * B_ + b) * L_ + l) * CK_ + j0] = o0;
    xg[(((size_t)k1 * B_ + b) * L_ + l) * CK_ + j1] = o1;
    __syncthreads();
  }
}

// ---------------- LN over channels + transpose-cast: xg f32 [kb][L][64] -> dst bf16 [kb][64][L] ----------------
__global__ __launch_bounds__(256) void k_lnt(const float* __restrict__ src, u16* __restrict__ dst,
                                             const void* __restrict__ g, const void* __restrict__ bb,
                                             int layer, int use_ln, const int* __restrict__ flagp){
  __shared__ float tile[64][65];
  int bf = *flagp;
  int z = blockIdx.x;
  int kb = z >> 3, lt = z & 7;
  int k = kb >> 5;
  const float* s = src + (size_t)kb * L_ * CK_ + (size_t)lt * 64 * CK_;
  int tid = threadIdx.x, lane = tid & 63, w = tid >> 6;
  float gj = 1.f, bj = 0.f;
  if (use_ln){
    gj = LD(g,  (size_t)(k * NL_ + layer) * CK_ + lane, bf);
    bj = LD(bb, (size_t)(k * NL_ + layer) * CK_ + lane, bf);
  }
  for (int i = 0; i < 16; i++){
    int row = w * 16 + i;
    float v = s[(size_t)row * CK_ + lane];
    float sum = v, sq = v * v;
#pragma unroll
    for (int o = 32; o > 0; o >>= 1){ sum += __shfl_xor(sum, o); sq += __shfl_xor(sq, o); }
    float nv = v;
    if (use_ln){
      float m = sum * (1.f / 64.f);
      float var = sq * (1.f / 64.f) - m * m;
      nv = (v - m) * rsqrtf(var + EPS_) * gj + bj;
    }
    tile[row][lane] = nv;
  }
  __syncthreads();
  int c = tid >> 2, seg = tid & 3;
  union { u16 s[8]; uint4 q; } u0, u1;
#pragma unroll
  for (int e = 0; e < 8; e++) u0.s[e] = f2bf(tile[seg * 16 + e][c]);
#pragma unroll
  for (int e = 0; e < 8; e++) u1.s[e] = f2bf(tile[seg * 16 + 8 + e][c]);
  u16* d = dst + (size_t)kb * CK_ * L_ + (size_t)c * L_ + lt * 64 + seg * 16;
  *reinterpret_cast<uint4*>(d)     = u0.q;
  *reinterpret_cast<uint4*>(d + 8) = u1.q;
}

// ---------------- fused mixer layer: time-mix + LN2 (LDS handoff) + FFN + LN1next/transpose ----------------
__global__ __launch_bounds__(256, 4) void k_mix(const u16* __restrict__ WtT, const u16* __restrict__ xin,
                                                float* __restrict__ xg,
                                                const void* __restrict__ bt,
                                                const void* __restrict__ ln2g, const void* __restrict__ ln2b,
                                                const u16* __restrict__ w1t, const u16* __restrict__ w2t,
                                                const void* __restrict__ bf1, const void* __restrict__ bf2,
                                                const void* __restrict__ ln1g, const void* __restrict__ ln1b,
                                                u16* __restrict__ xout, int layer,
                                                const int* __restrict__ flagp){
  __shared__ __align__(16) char lds[36864];
  u16* a_lds = (u16*)lds;              // [0,10240)   128*40
  u16* b_lds = (u16*)(lds + 10240);    // [10240,15360) 64*40
  u16* sm    = (u16*)lds;              // [0,18432)   128*72 (after time-mix)
  u16* wl    = (u16*)(lds + 18432);    // [18432,36864) 2 x 64*72
  int bf = *flagp;
  // XCD pinning
  int bid = blockIdx.x;
  int k = bid & 7, rr = bid >> 3;
  int b = rr & 31, mb = rr >> 5;       // mb in 0..3
  int m0 = mb * 128;
  const int klb = k * NL_ + layer;
  int kb = k * B_ + b;
  const u16* A  = WtT + ((size_t)klb * L_ + m0) * L_;
  const u16* Bm = xin + (size_t)kb * CK_ * L_;
  const u16* w1p = w1t + (size_t)klb * DF_ * CK_;
  const u16* w2p = w2t + (size_t)klb * CK_ * DF_;
  int tid = threadIdx.x, lane = tid & 63, w = tid >> 6, grp = lane >> 4, ln = lane & 15;

  // ===== phase 1: time mix =====
  int sa0 = tid, sa1 = tid + 256;
  int ra0 = sa0 >> 2, qa0 = (sa0 & 3) * 8;
  int ra1 = sa1 >> 2, qa1 = (sa1 & 3) * 8;
  int rb0 = tid >> 2, qb0 = (tid & 3) * 8;

  f32x4 acc[2][4];
#pragma unroll
  for (int i = 0; i < 2; i++)
#pragma unroll
    for (int j = 0; j < 4; j++) acc[i][j] = (f32x4){0.f, 0.f, 0.f, 0.f};

  uint4 va0 = *reinterpret_cast<const uint4*>(A + (size_t)ra0 * L_ + qa0);
  uint4 va1 = *reinterpret_cast<const uint4*>(A + (size_t)ra1 * L_ + qa1);
  uint4 vb0 = *reinterpret_cast<const uint4*>(Bm + (size_t)rb0 * L_ + qb0);

  for (int kk = 0; kk < 16; kk++){
    *reinterpret_cast<uint4*>(&a_lds[ra0 * 40 + qa0]) = va0;
    *reinterpret_cast<uint4*>(&a_lds[ra1 * 40 + qa1]) = va1;
    *reinterpret_cast<uint4*>(&b_lds[rb0 * 40 + qb0]) = vb0;
    uint4 na0, na1, nb0;
    if (kk < 15){
      int c0 = (kk + 1) * 32;
      na0 = *reinterpret_cast<const uint4*>(A + (size_t)ra0 * L_ + c0 + qa0);
      na1 = *reinterpret_cast<const uint4*>(A + (size_t)ra1 * L_ + c0 + qa1);
      nb0 = *reinterpret_cast<const uint4*>(Bm + (size_t)rb0 * L_ + c0 + qb0);
    }
    __syncthreads();
    bf16x8 af[2], bfr[4];
#pragma unroll
    for (int mt = 0; mt < 2; mt++)
      af[mt] = *reinterpret_cast<bf16x8*>(&a_lds[(w * 32 + mt * 16 + ln) * 40 + grp * 8]);
#pragma unroll
    for (int ct = 0; ct < 4; ct++)
      bfr[ct] = *reinterpret_cast<bf16x8*>(&b_lds[(ct * 16 + ln) * 40 + grp * 8]);
    __builtin_amdgcn_s_setprio(1);
#pragma unroll
    for (int mt = 0; mt < 2; mt++)
#pragma unroll
      for (int ct = 0; ct < 4; ct++)
        acc[mt][ct] = __builtin_amdgcn_mfma_f32_16x16x32_bf16(af[mt], bfr[ct], acc[mt][ct], 0, 0, 0);
    __builtin_amdgcn_s_setprio(0);
    __syncthreads();
    va0 = na0; va1 = na1; vb0 = nb0;
  }

  // weight staging indices (512 uint4 per matrix over 256 threads = 2 each)
  int wr0 = tid >> 3, wq0 = (tid & 7) * 8;
  int wr1 = wr0 + 32;
  // prefetch ft=0 weights (hide under LN2/epilogue)
  uint4 g1a = *reinterpret_cast<const uint4*>(w1p + (size_t)wr0 * CK_ + wq0);
  uint4 g1b = *reinterpret_cast<const uint4*>(w1p + (size_t)wr1 * CK_ + wq0);
  uint4 g2a = *reinterpret_cast<const uint4*>(w2p + (size_t)wr0 * DF_ + wq0);
  uint4 g2b = *reinterpret_cast<const uint4*>(w2p + (size_t)wr1 * DF_ + wq0);

  // ===== phase 2: residual RMW + LN2 -> sm (bf16, [row][c] layout) =====
  {
    float g2[4], b2[4];
#pragma unroll
    for (int ct = 0; ct < 4; ct++){
      int cc = ct * 16 + ln;
      g2[ct] = LD(ln2g, (size_t)klb * CK_ + cc, bf);
      b2[ct] = LD(ln2b, (size_t)klb * CK_ + cc, bf);
    }
    float* xgp = xg + (size_t)kb * L_ * CK_;
#pragma unroll
    for (int mt = 0; mt < 2; mt++){
#pragma unroll
      for (int r = 0; r < 4; r++){
        int rl = w * 32 + mt * 16 + grp * 4 + r;
        int m = m0 + rl;
        float bias = LD(bt, (size_t)klb * L_ + m, bf);
        float xn[4];
        float s = 0.f, sq = 0.f;
#pragma unroll
        for (int ct = 0; ct < 4; ct++){
          int cc = ct * 16 + ln;
          float y = fmaxf(acc[mt][ct][r] + bias, 0.f);
          float v = xgp[(size_t)m * CK_ + cc] + y;
          xgp[(size_t)m * CK_ + cc] = v;      // xg after time-mix (re-read in phase 4, L2-hot)
          xn[ct] = v; s += v; sq += v * v;
        }
#pragma unroll
        for (int o = 1; o < 16; o <<= 1){ s += __shfl_xor(s, o); sq += __shfl_xor(sq, o); }
        float mean = s * (1.f / 64.f);
        float var = sq * (1.f / 64.f) - mean * mean;
        float rstd = rsqrtf(var + EPS_);
#pragma unroll
        for (int ct = 0; ct < 4; ct++){
          int cc = ct * 16 + ln;
          sm[rl * 72 + cc] = f2bfn((xn[ct] - mean) * rstd * g2[ct] + b2[ct]);
        }
      }
    }
  }
  __syncthreads();

  // ===== phase 3: FFN (4 waves x 32 rows) =====
  bf16x8 faf[2][2];
#pragma unroll
  for (int mt = 0; mt < 2; mt++)
#pragma unroll
    for (int ks = 0; ks < 2; ks++)
      faf[mt][ks] = *reinterpret_cast<bf16x8*>(&sm[(w * 32 + mt * 16 + ln) * 72 + ks * 32 + grp * 8]);
  __syncthreads();   // sm rows now reusable as h (wave-private)

  f32x4 acc2[2][4];
#pragma unroll
  for (int i = 0; i < 2; i++)
#pragma unroll
    for (int j = 0; j < 4; j++) acc2[i][j] = (f32x4){0.f, 0.f, 0.f, 0.f};

#pragma unroll
  for (int ft = 0; ft < 8; ft++){
    *reinterpret_cast<uint4*>(&wl[wr0 * 72 + wq0]) = g1a;
    *reinterpret_cast<uint4*>(&wl[wr1 * 72 + wq0]) = g1b;
    *reinterpret_cast<uint4*>(&wl[4608 + wr0 * 72 + wq0]) = g2a;
    *reinterpret_cast<uint4*>(&wl[4608 + wr1 * 72 + wq0]) = g2b;
    if (ft < 7){
      g1a = *reinterpret_cast<const uint4*>(w1p + (size_t)((ft + 1) * 64 + wr0) * CK_ + wq0);
      g1b = *reinterpret_cast<const uint4*>(w1p + (size_t)((ft + 1) * 64 + wr1) * CK_ + wq0);
      g2a = *reinterpret_cast<const uint4*>(w2p + (size_t)wr0 * DF_ + (ft + 1) * 64 + wq0);
      g2b = *reinterpret_cast<const uint4*>(w2p + (size_t)wr1 * DF_ + (ft + 1) * 64 + wq0);
    }
    __syncthreads();

    f32x4 acc1[2][4];
#pragma unroll
    for (int i = 0; i < 2; i++)
#pragma unroll
      for (int j = 0; j < 4; j++) acc1[i][j] = (f32x4){0.f, 0.f, 0.f, 0.f};
    __builtin_amdgcn_s_setprio(1);
#pragma unroll
    for (int ks = 0; ks < 2; ks++)
#pragma unroll
      for (int n = 0; n < 4; n++){
        bf16x8 bb = *reinterpret_cast<bf16x8*>(&wl[(n * 16 + ln) * 72 + ks * 32 + grp * 8]);
#pragma unroll
        for (int mt = 0; mt < 2; mt++)
          acc1[mt][n] = __builtin_amdgcn_mfma_f32_16x16x32_bf16(faf[mt][ks], bb, acc1[mt][n], 0, 0, 0);
      }
    __builtin_amdgcn_s_setprio(0);
#pragma unroll
    for (int n = 0; n < 4; n++){
      float bias = LD(bf1, (size_t)klb * DF_ + ft * 64 + n * 16 + ln, bf);
#pragma unroll
      for (int mt = 0; mt < 2; mt++)
#pragma unroll
        for (int r = 0; r < 4; r++){
          float v = fmaxf(acc1[mt][n][r] + bias, 0.f);
          sm[(w * 32 + mt * 16 + grp * 4 + r) * 72 + n * 16 + ln] = f2bfn(v);
        }
    }
    __builtin_amdgcn_s_setprio(1);
#pragma unroll
    for (int ks = 0; ks < 2; ks++){
      bf16x8 hh[2];
#pragma unroll
      for (int mt = 0; mt < 2; mt++)
        hh[mt] = *reinterpret_cast<bf16x8*>(&sm[(w * 32 + mt * 16 + ln) * 72 + ks * 32 + grp * 8]);
#pragma unroll
      for (int n = 0; n < 4; n++){
        bf16x8 bb = *reinterpret_cast<bf16x8*>(&wl[4608 + (n * 16 + ln) * 72 + ks * 32 + grp * 8]);
#pragma unroll
        for (int mt = 0; mt < 2; mt++)
          acc2[mt][n] = __builtin_amdgcn_mfma_f32_16x16x32_bf16(hh[mt], bb, acc2[mt][n], 0, 0, 0);
      }
    }
    __builtin_amdgcn_s_setprio(0);
    __syncthreads();
  }

  // ===== phase 4: residual + next-layer LN1 (or cast) + transposed out =====
  const int next = layer + 1;
  const int use_ln = (next < NL_);
  float g1v[4], b1v[4], b2v[4];
#pragma unroll
  for (int n = 0; n < 4; n++){
    int cc = n * 16 + ln;
    b2v[n] = LD(bf2, (size_t)klb * CK_ + cc, bf);
    if (use_ln){
      g1v[n] = LD(ln1g, (size_t)(k * NL_ + next) * CK_ + cc, bf);
      b1v[n] = LD(ln1b, (size_t)(k * NL_ + next) * CK_ + cc, bf);
    } else { g1v[n] = 1.f; b1v[n] = 0.f; }
  }
  float* xgp = xg + ((size_t)kb * L_ + m0) * CK_;
#pragma unroll
  for (int mt = 0; mt < 2; mt++){
#pragma unroll
    for (int r = 0; r < 4; r++){
      int rl = w * 32 + mt * 16 + grp * 4 + r;
      float v[4];
      float s = 0.f, sq = 0.f;
#pragma unroll
      for (int n = 0; n < 4; n++){
        int cc = n * 16 + ln;
        float t = xgp[(size_t)rl * CK_ + cc] + acc2[mt][n][r] + b2v[n];
        if (use_ln) xgp[(size_t)rl * CK_ + cc] = t;   // final layer: xg dead, skip store
        v[n] = t; s += t; sq += t * t;
      }
      float mean = 0.f, rstd = 1.f;
      if (use_ln){
#pragma unroll
        for (int o = 1; o < 16; o <<= 1){ s += __shfl_xor(s, o); sq += __shfl_xor(sq, o); }
        mean = s * (1.f / 64.f);
        float var = sq * (1.f / 64.f) - mean * mean;
        rstd = rsqrtf(var + EPS_);
      }
#pragma unroll
      for (int n = 0; n < 4; n++){
        int cc = n * 16 + ln;
        sm[cc * 136 + rl] = f2bfn((v[n] - mean) * rstd * g1v[n] + b1v[n]);
      }
    }
  }
  __syncthreads();
  // coalesced transpose-out: xout[kb][c][m0 + off]
  u16* xsw = xout + (size_t)kb * CK_ * L_ + m0;
#pragma unroll
  for (int i = 0; i < 4; i++){
    int s = tid + i * 256;
    int c = s >> 4, off = (s & 15) * 8;
    *reinterpret_cast<uint4*>(xsw + (size_t)c * L_ + off) =
      *reinterpret_cast<uint4*>(&sm[c * 136 + off]);
  }
}

// ---------------- output projection + scatter + RevIN denorm ----------------
__global__ __launch_bounds__(384) void k_out(const u16* __restrict__ WoT, const u16* __restrict__ xgt,
                                             const int* __restrict__ idx, const void* __restrict__ bout,
                                             const void* __restrict__ revw, const void* __restrict__ revb,
                                             const float* __restrict__ meanw, const float* __restrict__ stdw,
                                             void* __restrict__ out, const int* __restrict__ flagp){
  __shared__ u16 a_lds[96 * 40];
  __shared__ u16 b_lds[64 * 40];
  int bf = *flagp;
  int b = blockIdx.x, k = blockIdx.y;
  int kb = k * B_ + b;
  const u16* A  = WoT + (size_t)k * P_ * L_;
  const u16* Bm = xgt + (size_t)kb * CK_ * L_;
  int tid = threadIdx.x, lane = tid & 63, w = tid >> 6, grp = lane >> 4, ln = lane & 15;
  f32x4 acc[4];
#pragma unroll
  for (int j = 0; j < 4; j++) acc[j] = (f32x4){0.f, 0.f, 0.f, 0.f};

  for (int kk = 0; kk < 16; kk++){
    {
      int row = tid >> 2, q = tid & 3;
      *reinterpret_cast<uint4*>(&a_lds[row * 40 + q * 8]) =
        *reinterpret_cast<const uint4*>(A + (size_t)row * L_ + kk * 32 + q * 8);
    }
    if (tid < 256){
      int row = tid >> 2, q = tid & 3;
      *reinterpret_cast<uint4*>(&b_lds[row * 40 + q * 8]) =
        *reinterpret_cast<const uint4*>(Bm + (size_t)row * L_ + kk * 32 + q * 8);
    }
    __syncthreads();
    bf16x8 af = *reinterpret_cast<bf16x8*>(&a_lds[(w * 16 + ln) * 40 + grp * 8]);
#pragma unroll
    for (int n = 0; n < 4; n++){
      bf16x8 bfr = *reinterpret_cast<bf16x8*>(&b_lds[(n * 16 + ln) * 40 + grp * 8]);
      acc[n] = __builtin_amdgcn_mfma_f32_16x16x32_bf16(af, bfr, acc[n], 0, 0, 0);
    }
    __syncthreads();
  }
#pragma unroll
  for (int n = 0; n < 4; n++){
    int j = n * 16 + ln;
    int c = idx[k * CK_ + j];
    float rw = LD(revw, c, bf), rb = LD(revb, c, bf);
    float sd = stdw[b * C_ + c], mn = meanw[b * C_ + c];
#pragma unroll
    for (int r = 0; r < 4; r++){
      int p = w * 16 + grp * 4 + r;
      float y = acc[n][r] + LD(bout, (size_t)k * P_ + p, bf);
      float val = (y - rb) / rw * sd + mn;
      size_t oi = ((size_t)b * P_ + p) * C_ + c;
      if (bf) ((u16*)out)[oi] = f2bf(val);
      else    ((float*)out)[oi] = val;
    }
  }
}

} // namespace

extern "C" void kernel_launch(void* const* d_in, const int* in_sizes, int n_in,
                              void* d_out, int out_size, void* d_ws, size_t ws_size,
                              hipStream_t stream){
  const void* x    = d_in[0];
  const int*  cid  = (const int*)d_in[1];
  const void* revw = d_in[2];
  const void* revb = d_in[3];
  const void* Wt   = d_in[4];
  const void* bt   = d_in[5];
  const void* ln1g = d_in[6];
  const void* ln1b = d_in[7];
  const void* Wf1  = d_in[8];
  const void* bf1  = d_in[9];
  const void* Wf2  = d_in[10];
  const void* bf2  = d_in[11];
  const void* ln2g = d_in[12];
  const void* ln2b = d_in[13];
  const void* Wout = d_in[14];
  const void* bout = d_in[15];
  char* ws = (char*)d_ws;

  int*   flag   = (int*)  (ws + 0);
  int*   idxp   = (int*)  (ws + 64);
  float* meanw  = (float*)(ws + 4096);
  float* stdw   = (float*)(ws + 69632);
  float* scalew = (float*)(ws + 135168);
  float* biasw  = (float*)(ws + 200704);
  float* psum   = (float*)(ws + 266240);    // 1MB
  float* psq    = (float*)(ws + 1314816);   // 1MB
  float* xg     = (float*)(ws + 2363392);   // 33.5MB
  u16*   xsA    = (u16*)  (ws + 35917824);  // ping-pong activation A ([kb][c][l], 16.8MB)
  u16*   WtT    = (u16*)  (ws + 52695040);
  u16*   Wf1T   = (u16*)  (ws + 61083648);
  u16*   Wf2T   = (u16*)  (ws + 62132224);
  u16*   WoT    = (u16*)  (ws + 63180800);
  u16*   xsB    = (u16*)  (ws + 63967232);  // ping-pong activation B; ends 80744448

  k_probe<<<1, 256, 0, stream>>>((const u32*)x, flag);
  k_sort<<<1, 512, 0, stream>>>(cid, idxp);
  k_trans<<<dim3(16, 16, 16), 256, 0, stream>>>(Wt,   WtT,  512, 512, flag);
  k_trans<<<dim3(16,  2, 16), 256, 0, stream>>>(Wf1,  Wf1T,  64, 512, flag);
  k_trans<<<dim3( 2, 16, 16), 256, 0, stream>>>(Wf2,  Wf2T, 512,  64, flag);
  k_trans<<<dim3( 3, 16,  8), 256, 0, stream>>>(Wout, WoT,  512,  96, flag);
  k_stats1<<<dim3(16, 32), 512, 0, stream>>>(x, psum, psq, flag);
  k_stats2<<<32, 512, 0, stream>>>(psum, psq, revw, revb, meanw, stdw, scalew, biasw, flag);
  k_gather<<<dim3(32, 32), 256, 0, stream>>>(x, idxp, scalew, biasw, xg, flag);

  // layer-0 LN1 + transpose -> xsA
  k_lnt<<<2048, 256, 0, stream>>>(xg, xsA, ln1g, ln1b, 0, 1, flag);
  // fused layers with ping-pong: L0 xsA->xsB, L1 xsB->xsA
  k_mix<<<1024, 256, 0, stream>>>(WtT, xsA, xg, bt, ln2g, ln2b, Wf1T, Wf2T,
                                  bf1, bf2, ln1g, ln1b, xsB, 0, flag);
  k_mix<<<1024, 256, 0, stream>>>(WtT, xsB, xg, bt, ln2g, ln2b, Wf1T, Wf2T,
                                  bf1, bf2, ln1g, ln1b, xsA, 1, flag);

  k_out<<<dim3(32, 8), 384, 0, stream>>>(WoT, xsA, idxp, bout, revw, revb, meanw, stdw, d_out, flag);
}

// Round 19
// 216.293 us; speedup vs baseline: 1.0713x; 1.0353x over previous
//
#include <hip/hip_runtime.h>

typedef unsigned short u16;
typedef unsigned int   u32;
typedef __attribute__((ext_vector_type(8))) __bf16 bf16x8;
typedef __attribute__((ext_vector_type(4))) float  f32x4;

#define DEV __device__ __forceinline__

namespace {

constexpr int B_  = 32;
constexpr int L_  = 512;
constexpr int P_  = 96;
constexpr int C_  = 512;
constexpr int K_  = 8;
constexpr int NL_ = 2;
constexpr int DF_ = 512;
constexpr int CK_ = 64;
constexpr float EPS_ = 1e-5f;

DEV float bf2f(u16 u){ union { u32 i; float f; } t; t.i = ((u32)u) << 16; return t.f; }
DEV u16 f2bf(float f){ union { float f; u32 i; } t; t.f = f;
  u32 r = t.i + 0x7fffu + ((t.i >> 16) & 1u); return (u16)(r >> 16); }
DEV u16 f2bfn(float f){ __bf16 h = (__bf16)f; u16 u; __builtin_memcpy(&u, &h, 2); return u; }
// dual-dtype load: bf==1 -> source is bf16 (u16), else fp32
DEV float LD(const void* p, size_t i, int bf){
  return bf ? bf2f(((const u16*)p)[i]) : ((const float*)p)[i];
}

// ---------------- dtype probe: bf16 low-half exponent signature ----------------
__global__ __launch_bounds__(256) void k_probe(const u32* __restrict__ x, int* __restrict__ flag){
  int cnt = 0;
  for (int i = threadIdx.x; i < 4096; i += 256){
    u32 w = x[i];
    u32 e = (w >> 7) & 0xFFu;
    cnt += (e >= 0x70u && e <= 0x8Fu) ? 1 : 0;
  }
#pragma unroll
  for (int o = 32; o > 0; o >>= 1) cnt += __shfl_xor(cnt, o);
  __shared__ int s[4];
  if ((threadIdx.x & 63) == 0) s[threadIdx.x >> 6] = cnt;
  __syncthreads();
  if (threadIdx.x == 0) flag[0] = (s[0] + s[1] + s[2] + s[3] > 2048) ? 1 : 0;
}

// ---------------- cluster argsort (stable counting sort) ----------------
__global__ __launch_bounds__(512) void k_sort(const int* __restrict__ cid, int* __restrict__ idx){
  __shared__ int bkt[C_];
  __shared__ int cnt[K_];
  __shared__ int off[K_];
  int c = threadIdx.x;
  int v = cid[c] % K_; if (v < 0) v += K_;
  bkt[c] = v;
  __syncthreads();
  if (c < K_){ int n = 0; for (int i = 0; i < C_; i++) n += (bkt[i] == c); cnt[c] = n; }
  __syncthreads();
  if (c == 0){ int s = 0; for (int k = 0; k < K_; k++){ off[k] = s; s += cnt[k]; } }
  __syncthreads();
  int r = 0;
  for (int i = 0; i < c; i++) r += (bkt[i] == bkt[c]);
  idx[off[bkt[c]] + r] = c;
}

// ---------------- batched transpose + cast to bf16: in[z][R][C] -> out[z][C][R] ----------------
__global__ __launch_bounds__(256) void k_trans(const void* __restrict__ in, u16* __restrict__ out,
                                               int R, int Cn, const int* __restrict__ flagp){
  __shared__ u16 t[32][36];
  int bf = *flagp;
  int z = blockIdx.z;
  int r0 = blockIdx.y * 32, c0 = blockIdx.x * 32;
  size_t base = (size_t)z * R * Cn;
  int tid = threadIdx.x;
  int i = tid >> 3, j4 = (tid & 7) * 4;
  size_t off = base + (size_t)(r0 + i) * Cn + c0 + j4;
  if (bf){
    ushort4 v = *reinterpret_cast<const ushort4*>((const u16*)in + off);
    t[i][j4 + 0] = v.x; t[i][j4 + 1] = v.y; t[i][j4 + 2] = v.z; t[i][j4 + 3] = v.w;
  } else {
    float4 v = *reinterpret_cast<const float4*>((const float*)in + off);
    t[i][j4 + 0] = f2bf(v.x); t[i][j4 + 1] = f2bf(v.y); t[i][j4 + 2] = f2bf(v.z); t[i][j4 + 3] = f2bf(v.w);
  }
  __syncthreads();
  ushort4 w;
  w.x = t[j4 + 0][i]; w.y = t[j4 + 1][i]; w.z = t[j4 + 2][i]; w.w = t[j4 + 3][i];
  *reinterpret_cast<ushort4*>(out + base + (size_t)(c0 + i) * R + r0 + j4) = w;
}

// ---------------- RevIN stats stage 1: partial sums over 32-timestep slices ----------------
__global__ __launch_bounds__(512) void k_stats1(const void* __restrict__ x,
                                                float* __restrict__ psum, float* __restrict__ psq,
                                                const int* __restrict__ flagp){
  int bf = *flagp;
  int ls = blockIdx.x, b = blockIdx.y, c = threadIdx.x;
  size_t base = ((size_t)b * L_ + (size_t)ls * 32) * C_ + c;
  float s = 0.f, sq = 0.f;
#pragma unroll 8
  for (int l = 0; l < 32; l++){
    float v = LD(x, base + (size_t)l * C_, bf);
    s += v; sq += v * v;
  }
  int o = (b * 16 + ls) * C_ + c;
  psum[o] = s; psq[o] = sq;
}

// ---------------- RevIN stats stage 2: fold partials -> mean/std + fused scale/bias ----------------
__global__ __launch_bounds__(512) void k_stats2(const float* __restrict__ psum, const float* __restrict__ psq,
                                                const void* __restrict__ revw, const void* __restrict__ revb,
                                                float* __restrict__ meanw, float* __restrict__ stdw,
                                                float* __restrict__ scalew, float* __restrict__ biasw,
                                                const int* __restrict__ flagp){
  int bf = *flagp;
  int b = blockIdx.x, c = threadIdx.x;
  float s = 0.f, sq = 0.f;
#pragma unroll
  for (int i = 0; i < 16; i++){
    s  += psum[(b * 16 + i) * C_ + c];
    sq += psq [(b * 16 + i) * C_ + c];
  }
  float m = s * (1.f / L_);
  float var = sq * (1.f / L_) - m * m;
  float sd = sqrtf(var + EPS_);
  meanw[b * C_ + c] = m;
  stdw [b * C_ + c] = sd;
  float sc = LD(revw, c, bf) / sd;
  scalew[b * C_ + c] = sc;
  biasw [b * C_ + c] = LD(revb, c, bf) - m * sc;
}

// ---------------- gather + RevIN normalize -> xg bf16 [K][B][L][CK] ----------------
__global__ __launch_bounds__(256) void k_gather(const void* __restrict__ x, const int* __restrict__ idx,
                                                const float* __restrict__ scalew, const float* __restrict__ biasw,
                                                u16* __restrict__ xg, const int* __restrict__ flagp){
  __shared__ float row[576];          // 512 + c>>3 skew padding
  int bf = *flagp;
  int lt = blockIdx.x, b = blockIdx.y;
  int tid = threadIdx.x;
  int oc0 = tid, oc1 = tid + 256;
  int c0 = idx[oc0], c1 = idx[oc1];
  float sc0 = scalew[b * C_ + c0], bs0 = biasw[b * C_ + c0];
  float sc1 = scalew[b * C_ + c1], bs1 = biasw[b * C_ + c1];
  int p0 = c0 + (c0 >> 3), p1 = c1 + (c1 >> 3);
  int k0 = oc0 >> 6, j0 = oc0 & 63;
  int k1 = oc1 >> 6, j1 = oc1 & 63;

  for (int r = 0; r < 16; r++){
    int l = lt * 16 + r;
    size_t base = ((size_t)b * L_ + l) * C_;
    if (bf){
      int i4 = tid * 2;
      ushort2 v = *reinterpret_cast<const ushort2*>((const u16*)x + base + i4);
      int a0 = i4, a1 = i4 + 1;
      row[a0 + (a0 >> 3)] = bf2f(v.x);
      row[a1 + (a1 >> 3)] = bf2f(v.y);
    } else {
      int i2 = tid * 2;
      float2 v = *reinterpret_cast<const float2*>((const float*)x + base + i2);
      int a0 = i2, a1 = i2 + 1;
      row[a0 + (a0 >> 3)] = v.x;
      row[a1 + (a1 >> 3)] = v.y;
    }
    __syncthreads();
    float o0 = row[p0] * sc0 + bs0;
    float o1 = row[p1] * sc1 + bs1;
    xg[(((size_t)k0 * B_ + b) * L_ + l) * CK_ + j0] = f2bfn(o0);
    xg[(((size_t)k1 * B_ + b) * L_ + l) * CK_ + j1] = f2bfn(o1);
    __syncthreads();
  }
}

// ---------------- LN over channels + transpose-cast: xg bf16 [kb][L][64] -> dst bf16 [kb][64][L] ----------------
__global__ __launch_bounds__(256) void k_lnt(const u16* __restrict__ src, u16* __restrict__ dst,
                                             const void* __restrict__ g, const void* __restrict__ bb,
                                             int layer, int use_ln, const int* __restrict__ flagp){
  __shared__ float tile[64][65];
  int bf = *flagp;
  int z = blockIdx.x;
  int kb = z >> 3, lt = z & 7;
  int k = kb >> 5;
  const u16* s = src + (size_t)kb * L_ * CK_ + (size_t)lt * 64 * CK_;
  int tid = threadIdx.x, lane = tid & 63, w = tid >> 6;
  float gj = 1.f, bj = 0.f;
  if (use_ln){
    gj = LD(g,  (size_t)(k * NL_ + layer) * CK_ + lane, bf);
    bj = LD(bb, (size_t)(k * NL_ + layer) * CK_ + lane, bf);
  }
  for (int i = 0; i < 16; i++){
    int row = w * 16 + i;
    float v = bf2f(s[(size_t)row * CK_ + lane]);
    float sum = v, sq = v * v;
#pragma unroll
    for (int o = 32; o > 0; o >>= 1){ sum += __shfl_xor(sum, o); sq += __shfl_xor(sq, o); }
    float nv = v;
    if (use_ln){
      float m = sum * (1.f / 64.f);
      float var = sq * (1.f / 64.f) - m * m;
      nv = (v - m) * rsqrtf(var + EPS_) * gj + bj;
    }
    tile[row][lane] = nv;
  }
  __syncthreads();
  int c = tid >> 2, seg = tid & 3;
  union { u16 s[8]; uint4 q; } u0, u1;
#pragma unroll
  for (int e = 0; e < 8; e++) u0.s[e] = f2bf(tile[seg * 16 + e][c]);
#pragma unroll
  for (int e = 0; e < 8; e++) u1.s[e] = f2bf(tile[seg * 16 + 8 + e][c]);
  u16* d = dst + (size_t)kb * CK_ * L_ + (size_t)c * L_ + lt * 64 + seg * 16;
  *reinterpret_cast<uint4*>(d)     = u0.q;
  *reinterpret_cast<uint4*>(d + 8) = u1.q;
}

// ---------------- fused mixer layer: time-mix + LN2 (LDS handoff) + FFN + LN1next/transpose ----------------
__global__ __launch_bounds__(256, 4) void k_mix(const u16* __restrict__ WtT, const u16* __restrict__ xin,
                                                u16* __restrict__ xg,
                                                const void* __restrict__ bt,
                                                const void* __restrict__ ln2g, const void* __restrict__ ln2b,
                                                const u16* __restrict__ w1t, const u16* __restrict__ w2t,
                                                const void* __restrict__ bf1, const void* __restrict__ bf2,
                                                const void* __restrict__ ln1g, const void* __restrict__ ln1b,
                                                u16* __restrict__ xout, int layer,
                                                const int* __restrict__ flagp){
  __shared__ __align__(16) char lds[36864];
  u16* a_lds = (u16*)lds;              // [0,10240)   128*40
  u16* b_lds = (u16*)(lds + 10240);    // [10240,15360) 64*40
  u16* sm    = (u16*)lds;              // [0,18432)   128*72 (after time-mix)
  u16* wl    = (u16*)(lds + 18432);    // [18432,36864) 2 x 64*72
  int bf = *flagp;
  // XCD pinning
  int bid = blockIdx.x;
  int k = bid & 7, rr = bid >> 3;
  int b = rr & 31, mb = rr >> 5;       // mb in 0..3
  int m0 = mb * 128;
  const int klb = k * NL_ + layer;
  int kb = k * B_ + b;
  const u16* A  = WtT + ((size_t)klb * L_ + m0) * L_;
  const u16* Bm = xin + (size_t)kb * CK_ * L_;
  const u16* w1p = w1t + (size_t)klb * DF_ * CK_;
  const u16* w2p = w2t + (size_t)klb * CK_ * DF_;
  int tid = threadIdx.x, lane = tid & 63, w = tid >> 6, grp = lane >> 4, ln = lane & 15;

  // ===== phase 1: time mix =====
  int sa0 = tid, sa1 = tid + 256;
  int ra0 = sa0 >> 2, qa0 = (sa0 & 3) * 8;
  int ra1 = sa1 >> 2, qa1 = (sa1 & 3) * 8;
  int rb0 = tid >> 2, qb0 = (tid & 3) * 8;

  f32x4 acc[2][4];
#pragma unroll
  for (int i = 0; i < 2; i++)
#pragma unroll
    for (int j = 0; j < 4; j++) acc[i][j] = (f32x4){0.f, 0.f, 0.f, 0.f};

  uint4 va0 = *reinterpret_cast<const uint4*>(A + (size_t)ra0 * L_ + qa0);
  uint4 va1 = *reinterpret_cast<const uint4*>(A + (size_t)ra1 * L_ + qa1);
  uint4 vb0 = *reinterpret_cast<const uint4*>(Bm + (size_t)rb0 * L_ + qb0);

  for (int kk = 0; kk < 16; kk++){
    *reinterpret_cast<uint4*>(&a_lds[ra0 * 40 + qa0]) = va0;
    *reinterpret_cast<uint4*>(&a_lds[ra1 * 40 + qa1]) = va1;
    *reinterpret_cast<uint4*>(&b_lds[rb0 * 40 + qb0]) = vb0;
    uint4 na0, na1, nb0;
    if (kk < 15){
      int c0 = (kk + 1) * 32;
      na0 = *reinterpret_cast<const uint4*>(A + (size_t)ra0 * L_ + c0 + qa0);
      na1 = *reinterpret_cast<const uint4*>(A + (size_t)ra1 * L_ + c0 + qa1);
      nb0 = *reinterpret_cast<const uint4*>(Bm + (size_t)rb0 * L_ + c0 + qb0);
    }
    __syncthreads();
    bf16x8 af[2], bfr[4];
#pragma unroll
    for (int mt = 0; mt < 2; mt++)
      af[mt] = *reinterpret_cast<bf16x8*>(&a_lds[(w * 32 + mt * 16 + ln) * 40 + grp * 8]);
#pragma unroll
    for (int ct = 0; ct < 4; ct++)
      bfr[ct] = *reinterpret_cast<bf16x8*>(&b_lds[(ct * 16 + ln) * 40 + grp * 8]);
    __builtin_amdgcn_s_setprio(1);
#pragma unroll
    for (int mt = 0; mt < 2; mt++)
#pragma unroll
      for (int ct = 0; ct < 4; ct++)
        acc[mt][ct] = __builtin_amdgcn_mfma_f32_16x16x32_bf16(af[mt], bfr[ct], acc[mt][ct], 0, 0, 0);
    __builtin_amdgcn_s_setprio(0);
    __syncthreads();
    va0 = na0; va1 = na1; vb0 = nb0;
  }

  // weight staging indices (512 uint4 per matrix over 256 threads = 2 each)
  int wr0 = tid >> 3, wq0 = (tid & 7) * 8;
  int wr1 = wr0 + 32;
  // prefetch ft=0 weights (hide under LN2/epilogue)
  uint4 g1a = *reinterpret_cast<const uint4*>(w1p + (size_t)wr0 * CK_ + wq0);
  uint4 g1b = *reinterpret_cast<const uint4*>(w1p + (size_t)wr1 * CK_ + wq0);
  uint4 g2a = *reinterpret_cast<const uint4*>(w2p + (size_t)wr0 * DF_ + wq0);
  uint4 g2b = *reinterpret_cast<const uint4*>(w2p + (size_t)wr1 * DF_ + wq0);

  // ===== phase 2: residual RMW (bf16 xg) + LN2 -> sm =====
  {
    float g2[4], b2[4];
#pragma unroll
    for (int ct = 0; ct < 4; ct++){
      int cc = ct * 16 + ln;
      g2[ct] = LD(ln2g, (size_t)klb * CK_ + cc, bf);
      b2[ct] = LD(ln2b, (size_t)klb * CK_ + cc, bf);
    }
    u16* xgp = xg + (size_t)kb * L_ * CK_;
#pragma unroll
    for (int mt = 0; mt < 2; mt++){
#pragma unroll
      for (int r = 0; r < 4; r++){
        int rl = w * 32 + mt * 16 + grp * 4 + r;
        int m = m0 + rl;
        float bias = LD(bt, (size_t)klb * L_ + m, bf);
        float xn[4];
        float s = 0.f, sq = 0.f;
#pragma unroll
        for (int ct = 0; ct < 4; ct++){
          int cc = ct * 16 + ln;
          float y = fmaxf(acc[mt][ct][r] + bias, 0.f);
          float v = bf2f(xgp[(size_t)m * CK_ + cc]) + y;
          xgp[(size_t)m * CK_ + cc] = f2bfn(v);   // re-read in phase 4 (L2-hot)
          xn[ct] = v; s += v; sq += v * v;
        }
#pragma unroll
        for (int o = 1; o < 16; o <<= 1){ s += __shfl_xor(s, o); sq += __shfl_xor(sq, o); }
        float mean = s * (1.f / 64.f);
        float var = sq * (1.f / 64.f) - mean * mean;
        float rstd = rsqrtf(var + EPS_);
#pragma unroll
        for (int ct = 0; ct < 4; ct++){
          int cc = ct * 16 + ln;
          sm[rl * 72 + cc] = f2bfn((xn[ct] - mean) * rstd * g2[ct] + b2[ct]);
        }
      }
    }
  }
  __syncthreads();

  // ===== phase 3: FFN (4 waves x 32 rows) =====
  bf16x8 faf[2][2];
#pragma unroll
  for (int mt = 0; mt < 2; mt++)
#pragma unroll
    for (int ks = 0; ks < 2; ks++)
      faf[mt][ks] = *reinterpret_cast<bf16x8*>(&sm[(w * 32 + mt * 16 + ln) * 72 + ks * 32 + grp * 8]);
  __syncthreads();   // sm rows now reusable as h (wave-private)

  f32x4 acc2[2][4];
#pragma unroll
  for (int i = 0; i < 2; i++)
#pragma unroll
    for (int j = 0; j < 4; j++) acc2[i][j] = (f32x4){0.f, 0.f, 0.f, 0.f};

#pragma unroll
  for (int ft = 0; ft < 8; ft++){
    *reinterpret_cast<uint4*>(&wl[wr0 * 72 + wq0]) = g1a;
    *reinterpret_cast<uint4*>(&wl[wr1 * 72 + wq0]) = g1b;
    *reinterpret_cast<uint4*>(&wl[4608 + wr0 * 72 + wq0]) = g2a;
    *reinterpret_cast<uint4*>(&wl[4608 + wr1 * 72 + wq0]) = g2b;
    if (ft < 7){
      g1a = *reinterpret_cast<const uint4*>(w1p + (size_t)((ft + 1) * 64 + wr0) * CK_ + wq0);
      g1b = *reinterpret_cast<const uint4*>(w1p + (size_t)((ft + 1) * 64 + wr1) * CK_ + wq0);
      g2a = *reinterpret_cast<const uint4*>(w2p + (size_t)wr0 * DF_ + (ft + 1) * 64 + wq0);
      g2b = *reinterpret_cast<const uint4*>(w2p + (size_t)wr1 * DF_ + (ft + 1) * 64 + wq0);
    }
    __syncthreads();

    f32x4 acc1[2][4];
#pragma unroll
    for (int i = 0; i < 2; i++)
#pragma unroll
      for (int j = 0; j < 4; j++) acc1[i][j] = (f32x4){0.f, 0.f, 0.f, 0.f};
    __builtin_amdgcn_s_setprio(1);
#pragma unroll
    for (int ks = 0; ks < 2; ks++)
#pragma unroll
      for (int n = 0; n < 4; n++){
        bf16x8 bb = *reinterpret_cast<bf16x8*>(&wl[(n * 16 + ln) * 72 + ks * 32 + grp * 8]);
#pragma unroll
        for (int mt = 0; mt < 2; mt++)
          acc1[mt][n] = __builtin_amdgcn_mfma_f32_16x16x32_bf16(faf[mt][ks], bb, acc1[mt][n], 0, 0, 0);
      }
    __builtin_amdgcn_s_setprio(0);
#pragma unroll
    for (int n = 0; n < 4; n++){
      float bias = LD(bf1, (size_t)klb * DF_ + ft * 64 + n * 16 + ln, bf);
#pragma unroll
      for (int mt = 0; mt < 2; mt++)
#pragma unroll
        for (int r = 0; r < 4; r++){
          float v = fmaxf(acc1[mt][n][r] + bias, 0.f);
          sm[(w * 32 + mt * 16 + grp * 4 + r) * 72 + n * 16 + ln] = f2bfn(v);
        }
    }
    __builtin_amdgcn_s_setprio(1);
#pragma unroll
    for (int ks = 0; ks < 2; ks++){
      bf16x8 hh[2];
#pragma unroll
      for (int mt = 0; mt < 2; mt++)
        hh[mt] = *reinterpret_cast<bf16x8*>(&sm[(w * 32 + mt * 16 + ln) * 72 + ks * 32 + grp * 8]);
#pragma unroll
      for (int n = 0; n < 4; n++){
        bf16x8 bb = *reinterpret_cast<bf16x8*>(&wl[4608 + (n * 16 + ln) * 72 + ks * 32 + grp * 8]);
#pragma unroll
        for (int mt = 0; mt < 2; mt++)
          acc2[mt][n] = __builtin_amdgcn_mfma_f32_16x16x32_bf16(hh[mt], bb, acc2[mt][n], 0, 0, 0);
      }
    }
    __builtin_amdgcn_s_setprio(0);
    __syncthreads();
  }

  // ===== phase 4: residual + next-layer LN1 (or cast) + transposed out =====
  const int next = layer + 1;
  const int use_ln = (next < NL_);
  float g1v[4], b1v[4], b2v[4];
#pragma unroll
  for (int n = 0; n < 4; n++){
    int cc = n * 16 + ln;
    b2v[n] = LD(bf2, (size_t)klb * CK_ + cc, bf);
    if (use_ln){
      g1v[n] = LD(ln1g, (size_t)(k * NL_ + next) * CK_ + cc, bf);
      b1v[n] = LD(ln1b, (size_t)(k * NL_ + next) * CK_ + cc, bf);
    } else { g1v[n] = 1.f; b1v[n] = 0.f; }
  }
  u16* xgp = xg + ((size_t)kb * L_ + m0) * CK_;
#pragma unroll
  for (int mt = 0; mt < 2; mt++){
#pragma unroll
    for (int r = 0; r < 4; r++){
      int rl = w * 32 + mt * 16 + grp * 4 + r;
      float v[4];
      float s = 0.f, sq = 0.f;
#pragma unroll
      for (int n = 0; n < 4; n++){
        int cc = n * 16 + ln;
        float t = bf2f(xgp[(size_t)rl * CK_ + cc]) + acc2[mt][n][r] + b2v[n];
        if (use_ln) xgp[(size_t)rl * CK_ + cc] = f2bfn(t);   // only needed for next layer
        v[n] = t; s += t; sq += t * t;
      }
      float mean = 0.f, rstd = 1.f;
      if (use_ln){
#pragma unroll
        for (int o = 1; o < 16; o <<= 1){ s += __shfl_xor(s, o); sq += __shfl_xor(sq, o); }
        mean = s * (1.f / 64.f);
        float var = sq * (1.f / 64.f) - mean * mean;
        rstd = rsqrtf(var + EPS_);
      }
#pragma unroll
      for (int n = 0; n < 4; n++){
        int cc = n * 16 + ln;
        sm[cc * 136 + rl] = f2bfn((v[n] - mean) * rstd * g1v[n] + b1v[n]);
      }
    }
  }
  __syncthreads();
  // coalesced transpose-out: xout[kb][c][m0 + off]
  u16* xsw = xout + (size_t)kb * CK_ * L_ + m0;
#pragma unroll
  for (int i = 0; i < 4; i++){
    int s = tid + i * 256;
    int c = s >> 4, off = (s & 15) * 8;
    *reinterpret_cast<uint4*>(xsw + (size_t)c * L_ + off) =
      *reinterpret_cast<uint4*>(&sm[c * 136 + off]);
  }
}

// ---------------- output projection + scatter + RevIN denorm ----------------
__global__ __launch_bounds__(384) void k_out(const u16* __restrict__ WoT, const u16* __restrict__ xgt,
                                             const int* __restrict__ idx, const void* __restrict__ bout,
                                             const void* __restrict__ revw, const void* __restrict__ revb,
                                             const float* __restrict__ meanw, const float* __restrict__ stdw,
                                             void* __restrict__ out, const int* __restrict__ flagp){
  __shared__ u16 a_lds[96 * 40];
  __shared__ u16 b_lds[64 * 40];
  int bf = *flagp;
  int b = blockIdx.x, k = blockIdx.y;
  int kb = k * B_ + b;
  const u16* A  = WoT + (size_t)k * P_ * L_;
  const u16* Bm = xgt + (size_t)kb * CK_ * L_;
  int tid = threadIdx.x, lane = tid & 63, w = tid >> 6, grp = lane >> 4, ln = lane & 15;
  f32x4 acc[4];
#pragma unroll
  for (int j = 0; j < 4; j++) acc[j] = (f32x4){0.f, 0.f, 0.f, 0.f};

  for (int kk = 0; kk < 16; kk++){
    {
      int row = tid >> 2, q = tid & 3;
      *reinterpret_cast<uint4*>(&a_lds[row * 40 + q * 8]) =
        *reinterpret_cast<const uint4*>(A + (size_t)row * L_ + kk * 32 + q * 8);
    }
    if (tid < 256){
      int row = tid >> 2, q = tid & 3;
      *reinterpret_cast<uint4*>(&b_lds[row * 40 + q * 8]) =
        *reinterpret_cast<const uint4*>(Bm + (size_t)row * L_ + kk * 32 + q * 8);
    }
    __syncthreads();
    bf16x8 af = *reinterpret_cast<bf16x8*>(&a_lds[(w * 16 + ln) * 40 + grp * 8]);
#pragma unroll
    for (int n = 0; n < 4; n++){
      bf16x8 bfr = *reinterpret_cast<bf16x8*>(&b_lds[(n * 16 + ln) * 40 + grp * 8]);
      acc[n] = __builtin_amdgcn_mfma_f32_16x16x32_bf16(af, bfr, acc[n], 0, 0, 0);
    }
    __syncthreads();
  }
#pragma unroll
  for (int n = 0; n < 4; n++){
    int j = n * 16 + ln;
    int c = idx[k * CK_ + j];
    float rw = LD(revw, c, bf), rb = LD(revb, c, bf);
    float sd = stdw[b * C_ + c], mn = meanw[b * C_ + c];
#pragma unroll
    for (int r = 0; r < 4; r++){
      int p = w * 16 + grp * 4 + r;
      float y = acc[n][r] + LD(bout, (size_t)k * P_ + p, bf);
      float val = (y - rb) / rw * sd + mn;
      size_t oi = ((size_t)b * P_ + p) * C_ + c;
      if (bf) ((u16*)out)[oi] = f2bf(val);
      else    ((float*)out)[oi] = val;
    }
  }
}

} // namespace

extern "C" void kernel_launch(void* const* d_in, const int* in_sizes, int n_in,
                              void* d_out, int out_size, void* d_ws, size_t ws_size,
                              hipStream_t stream){
  const void* x    = d_in[0];
  const int*  cid  = (const int*)d_in[1];
  const void* revw = d_in[2];
  const void* revb = d_in[3];
  const void* Wt   = d_in[4];
  const void* bt   = d_in[5];
  const void* ln1g = d_in[6];
  const void* ln1b = d_in[7];
  const void* Wf1  = d_in[8];
  const void* bf1  = d_in[9];
  const void* Wf2  = d_in[10];
  const void* bf2  = d_in[11];
  const void* ln2g = d_in[12];
  const void* ln2b = d_in[13];
  const void* Wout = d_in[14];
  const void* bout = d_in[15];
  char* ws = (char*)d_ws;

  int*   flag   = (int*)  (ws + 0);
  int*   idxp   = (int*)  (ws + 64);
  float* meanw  = (float*)(ws + 4096);
  float* stdw   = (float*)(ws + 69632);
  float* scalew = (float*)(ws + 135168);
  float* biasw  = (float*)(ws + 200704);
  float* psum   = (float*)(ws + 266240);    // 1MB
  float* psq    = (float*)(ws + 1314816);   // 1MB
  u16*   xg     = (u16*)  (ws + 2363392);   // residual stream, bf16, 16.8MB
  u16*   xsA    = (u16*)  (ws + 19140608);  // ping-pong activation A ([kb][c][l], 16.8MB)
  u16*   WtT    = (u16*)  (ws + 35917824);  // 8.4MB
  u16*   Wf1T   = (u16*)  (ws + 44306432);  // 1MB
  u16*   Wf2T   = (u16*)  (ws + 45355008);  // 1MB
  u16*   WoT    = (u16*)  (ws + 46403584);  // 0.8MB
  u16*   xsB    = (u16*)  (ws + 47190016);  // ping-pong activation B; ends 63967232

  k_probe<<<1, 256, 0, stream>>>((const u32*)x, flag);
  k_sort<<<1, 512, 0, stream>>>(cid, idxp);
  k_trans<<<dim3(16, 16, 16), 256, 0, stream>>>(Wt,   WtT,  512, 512, flag);
  k_trans<<<dim3(16,  2, 16), 256, 0, stream>>>(Wf1,  Wf1T,  64, 512, flag);
  k_trans<<<dim3( 2, 16, 16), 256, 0, stream>>>(Wf2,  Wf2T, 512,  64, flag);
  k_trans<<<dim3( 3, 16,  8), 256, 0, stream>>>(Wout, WoT,  512,  96, flag);
  k_stats1<<<dim3(16, 32), 512, 0, stream>>>(x, psum, psq, flag);
  k_stats2<<<32, 512, 0, stream>>>(psum, psq, revw, revb, meanw, stdw, scalew, biasw, flag);
  k_gather<<<dim3(32, 32), 256, 0, stream>>>(x, idxp, scalew, biasw, xg, flag);

  // layer-0 LN1 + transpose -> xsA
  k_lnt<<<2048, 256, 0, stream>>>(xg, xsA, ln1g, ln1b, 0, 1, flag);
  // fused layers with ping-pong: L0 xsA->xsB, L1 xsB->xsA
  k_mix<<<1024, 256, 0, stream>>>(WtT, xsA, xg, bt, ln2g, ln2b, Wf1T, Wf2T,
                                  bf1, bf2, ln1g, ln1b, xsB, 0, flag);
  k_mix<<<1024, 256, 0, stream>>>(WtT, xsB, xg, bt, ln2g, ln2b, Wf1T, Wf2T,
                                  bf1, bf2, ln1g, ln1b, xsA, 1, flag);

  k_out<<<dim3(32, 8), 384, 0, stream>>>(WoT, xsA, idxp, bout, revw, revb, meanw, stdw, d_out, flag);
}